// Round 3
// baseline (865.175 us; speedup 1.0000x reference)
//
#include <hip/hip_runtime.h>
#include <hip/hip_bf16.h>
#include <math.h>

// All tensor inputs are float32; output is float32 (64 sigmoid values).
// Key algebraic reductions vs reference:
//  - psi branch (3x [N,128] matmuls + segment-mean) enters ONLY as a
//    per-(segment,head) additive constant on preattn -> cancels exactly in
//    segment softmax -> dead code, skipped entirely.
//  - preattn = collected @ wq_eff, wq_eff[48,4] = W_k[:48]·W_q^T/8, precomputed.
//  - collected is [10 pos | 1 value | 37 one-hot] -> phi layer 0 is 11 dense
//    rows + 1 gathered row of W0; `collected` never materialized.

#define BSEG 64
#define TLEN 4096
#define NPART 9          // 8 main chunks + 1 demo partial per segment
#define PART_STRIDE 520  // m[4], s[4], pacc[4*128]

// ws layout (float offsets)
#define OFF_DEMO 0                 // demo_enc 64*48
#define OFF_WQ   3072              // wq_eff 48*4
#define OFF_PARTIALS 3264          // 64*9*520 floats

static __device__ __forceinline__ float bfbits2f(unsigned v) { return __uint_as_float(v << 16); }
static __device__ __forceinline__ unsigned short f2bf_rne(float x) {
  unsigned u = __float_as_uint(x);
  unsigned r = (u + 0x7FFFu + ((u >> 16) & 1u)) >> 16;
  return (unsigned short)r;
}

// ---------------- K1: demo encoder + wq_eff ----------------
__global__ __launch_bounds__(256) void k_prep(
    const float* __restrict__ demo, const float* __restrict__ dW1, const float* __restrict__ db1,
    const float* __restrict__ dW2, const float* __restrict__ db2,
    const float* __restrict__ Wk, const float* __restrict__ Wq, float* __restrict__ ws) {
  __shared__ float dl[64 * 8];
  __shared__ float hd[64 * 128];
  int tid = threadIdx.x;
  for (int i = tid; i < 512; i += 256) dl[i] = demo[i];
  __syncthreads();
  for (int idx = tid; idx < 8192; idx += 256) {
    int r = idx >> 7, c = idx & 127;
    float a = db1[c];
#pragma unroll
    for (int i = 0; i < 8; ++i) a = fmaf(dl[r * 8 + i], dW1[i * 128 + c], a);
    hd[idx] = fmaxf(a, 0.f);
  }
  __syncthreads();
  for (int idx = tid; idx < 3072; idx += 256) {
    int r = idx / 48, c = idx % 48;
    float a = db2[c];
    for (int k = 0; k < 128; ++k) a = fmaf(hd[r * 128 + k], dW2[k * 48 + c], a);
    ws[OFF_DEMO + idx] = a;   // no relu on demo-encoder output
  }
  if (tid < 192) {
    int i = tid >> 2, h = tid & 3;
    float a = 0.f;
    for (int d = 0; d < 64; ++d) a = fmaf(Wk[i * 256 + h * 64 + d], Wq[h * 64 + d], a);
    ws[OFF_WQ + tid] = a * 0.125f;   // 1/sqrt(64)
  }
}

// ---------------- GEMM core: [64x128] = relu([64x128] @ W[128x128] + b) ----------
// Activations in LDS as bf16, row stride 136. W/bias fp32 from global (L2-hot).
// Thread tile: 4 rows x 8 cols on a 16x16 thread grid.
static __device__ __forceinline__ void gemm64x128(
    const float* __restrict__ W, const float* __restrict__ bias,
    const unsigned short* hin, unsigned short* hout, int tid) {
  const int ct = tid & 15, rt = tid >> 4;
  const int c0 = ct * 8, r0 = rt * 4;
  float acc[4][8];
  {
    float4 bv0 = *(const float4*)(bias + c0);
    float4 bv1 = *(const float4*)(bias + c0 + 4);
#pragma unroll
    for (int i = 0; i < 4; ++i) {
      acc[i][0] = bv0.x; acc[i][1] = bv0.y; acc[i][2] = bv0.z; acc[i][3] = bv0.w;
      acc[i][4] = bv1.x; acc[i][5] = bv1.y; acc[i][6] = bv1.z; acc[i][7] = bv1.w;
    }
  }
  for (int k4 = 0; k4 < 128; k4 += 4) {
    float hv[4][4];
#pragma unroll
    for (int i = 0; i < 4; ++i) {
      uint2 hw = *(const uint2*)(hin + (r0 + i) * 136 + k4);
      hv[i][0] = bfbits2f(hw.x & 0xFFFFu);
      hv[i][1] = __uint_as_float(hw.x & 0xFFFF0000u);
      hv[i][2] = bfbits2f(hw.y & 0xFFFFu);
      hv[i][3] = __uint_as_float(hw.y & 0xFFFF0000u);
    }
#pragma unroll
    for (int kk = 0; kk < 4; ++kk) {
      float4 w0 = *(const float4*)(W + (k4 + kk) * 128 + c0);
      float4 w1 = *(const float4*)(W + (k4 + kk) * 128 + c0 + 4);
      float wv[8] = {w0.x, w0.y, w0.z, w0.w, w1.x, w1.y, w1.z, w1.w};
#pragma unroll
      for (int i = 0; i < 4; ++i)
#pragma unroll
        for (int j = 0; j < 8; ++j)
          acc[i][j] = fmaf(hv[i][kk], wv[j], acc[i][j]);
    }
  }
#pragma unroll
  for (int i = 0; i < 4; ++i) {
    unsigned p0 = (unsigned)f2bf_rne(fmaxf(acc[i][0], 0.f)) | ((unsigned)f2bf_rne(fmaxf(acc[i][1], 0.f)) << 16);
    unsigned p1 = (unsigned)f2bf_rne(fmaxf(acc[i][2], 0.f)) | ((unsigned)f2bf_rne(fmaxf(acc[i][3], 0.f)) << 16);
    unsigned p2 = (unsigned)f2bf_rne(fmaxf(acc[i][4], 0.f)) | ((unsigned)f2bf_rne(fmaxf(acc[i][5], 0.f)) << 16);
    unsigned p3 = (unsigned)f2bf_rne(fmaxf(acc[i][6], 0.f)) | ((unsigned)f2bf_rne(fmaxf(acc[i][7], 0.f)) << 16);
    *(uint4*)(hout + (r0 + i) * 136 + c0) = make_uint4(p0, p1, p2, p3);
  }
}

// ---------------- K2: demo rows (row 0 of each segment) -> partial p=8 ----------------
__global__ __launch_bounds__(256) void k_demo(
    const float* __restrict__ ws,
    const float* __restrict__ W0, const float* __restrict__ b0,
    const float* __restrict__ W1, const float* __restrict__ b1,
    const float* __restrict__ W2, const float* __restrict__ b2,
    const float* __restrict__ W3, const float* __restrict__ b3,
    float* __restrict__ part) {
  __shared__ float x[64 * 48];
  __shared__ __align__(16) unsigned short hA[64 * 136];
  __shared__ __align__(16) unsigned short hB[64 * 136];
  __shared__ float pre[256];
  int tid = threadIdx.x;
  for (int i = tid; i < 3072; i += 256) x[i] = ws[OFF_DEMO + i];
  __syncthreads();
  { // preattn for demo rows: dense 48-dot with wq_eff
    int r = tid >> 2, h = tid & 3;
    float a = 0.f;
    for (int i = 0; i < 48; ++i) a = fmaf(x[r * 48 + i], ws[OFF_WQ + i * 4 + h], a);
    pre[tid] = a;
  }
  { // layer 0: dense 48 -> 128
    int rl = tid & 63, cg = tid >> 6;
    float4 a[8];
    const float* bp = b0 + cg * 32;
#pragma unroll
    for (int j = 0; j < 8; ++j) a[j] = *(const float4*)(bp + j * 4);
    for (int i = 0; i < 48; ++i) {
      float xi = x[rl * 48 + i];
      const float* wr = W0 + i * 128 + cg * 32;
#pragma unroll
      for (int j = 0; j < 8; ++j) {
        float4 w = *(const float4*)(wr + j * 4);
        a[j].x = fmaf(xi, w.x, a[j].x); a[j].y = fmaf(xi, w.y, a[j].y);
        a[j].z = fmaf(xi, w.z, a[j].z); a[j].w = fmaf(xi, w.w, a[j].w);
      }
    }
#pragma unroll
    for (int j = 0; j < 8; ++j) {
      unsigned q0 = (unsigned)f2bf_rne(fmaxf(a[j].x, 0.f)) | ((unsigned)f2bf_rne(fmaxf(a[j].y, 0.f)) << 16);
      unsigned q1 = (unsigned)f2bf_rne(fmaxf(a[j].z, 0.f)) | ((unsigned)f2bf_rne(fmaxf(a[j].w, 0.f)) << 16);
      *(uint2*)(hA + rl * 136 + cg * 32 + j * 4) = make_uint2(q0, q1);
    }
  }
  __syncthreads();
  gemm64x128(W1, b1, hA, hB, tid); __syncthreads();
  gemm64x128(W2, b2, hB, hA, tid); __syncthreads();
  gemm64x128(W3, b3, hA, hB, tid); __syncthreads();
  { // partial p=8 per segment r: m=pre, s=1 (e=exp(0)=1)
    int r = tid >> 2, h = tid & 3;
    float* P = part + (r * NPART + 8) * PART_STRIDE;
    P[h] = pre[tid];
    P[4 + h] = 1.f;
  }
  for (int i = tid; i < 64 * 512; i += 256) {
    int r = i >> 9, rem = i & 511, l = rem & 127;
    part[(r * NPART + 8) * PART_STRIDE + 8 + rem] = bfbits2f(hB[r * 136 + l]);
  }
}

// ---------------- K3: main — 64 segments x 8 chunks of 512 time rows ----------------
__global__ __launch_bounds__(256, 2) void k_main(
    const float* __restrict__ times, const float* __restrict__ values,
    const int* __restrict__ meas, const float* __restrict__ tsc,
    const float* __restrict__ ws,
    const float* __restrict__ W0, const float* __restrict__ b0,
    const float* __restrict__ W1, const float* __restrict__ b1,
    const float* __restrict__ W2, const float* __restrict__ b2,
    const float* __restrict__ W3, const float* __restrict__ b3,
    float* __restrict__ part) {
  __shared__ __align__(16) unsigned short hA[64 * 136];
  __shared__ __align__(16) unsigned short hB[64 * 136];
  __shared__ float preb[512 * 4];
  __shared__ float maxred[256 * 4];
  __shared__ float elds[64 * 4];
  __shared__ float wql[192];
  __shared__ float mblk[4];
  int tid = threadIdx.x;
  int b = blockIdx.x >> 3, c = blockIdx.x & 7;
  int t0 = c << 9;
  if (tid < 192) wql[tid] = ws[OFF_WQ + tid];
  float invts[5];
#pragma unroll
  for (int i = 0; i < 5; ++i) invts[i] = 1.f / tsc[i];
  __syncthreads();

  // ---- phase A: preattn + block max over this chunk's 512 rows ----
  float mloc[4] = {-1e30f, -1e30f, -1e30f, -1e30f};
  for (int rr = 0; rr < 2; ++rr) {
    int r = tid + rr * 256;
    int t = t0 + r;
    float tv = times[b * TLEN + t];
    float vv = values[b * TLEN + t];
    int mm = meas[b * TLEN + t];
    float f[11];
#pragma unroll
    for (int i = 0; i < 5; ++i) { float s = tv * invts[i]; f[i] = sinf(s); f[5 + i] = cosf(s); }
    f[10] = vv;
#pragma unroll
    for (int h = 0; h < 4; ++h) {
      float a = wql[(11 + mm) * 4 + h];   // one-hot row
#pragma unroll
      for (int i = 0; i < 11; ++i) a = fmaf(f[i], wql[i * 4 + h], a);
      preb[r * 4 + h] = a;
      mloc[h] = fmaxf(mloc[h], a);
    }
  }
#pragma unroll
  for (int h = 0; h < 4; ++h) maxred[tid * 4 + h] = mloc[h];
  __syncthreads();
  for (int s = 128; s > 0; s >>= 1) {
    if (tid < s) {
#pragma unroll
      for (int h = 0; h < 4; ++h)
        maxred[tid * 4 + h] = fmaxf(maxred[tid * 4 + h], maxred[(tid + s) * 4 + h]);
    }
    __syncthreads();
  }
  if (tid < 4) mblk[tid] = maxred[tid];
  __syncthreads();

  // ---- phase B: 8 tiles of 64 rows: fused phi chain + weighted accumulation ----
  float pacc0 = 0.f, pacc1 = 0.f, sacc0 = 0.f, sacc1 = 0.f;
  const int hh0 = tid >> 7, ll = tid & 127;   // thread owns (hh0, ll) and (hh0+2, ll)
  const int rl = tid & 63, cg = tid >> 6;
  for (int tile = 0; tile < 8; ++tile) {
    int rb = tile << 6;
    { // e = exp(pre - m)
      int er = tid >> 2, eh = tid & 3;
      elds[tid] = expf(preb[(rb + er) * 4 + eh] - mblk[eh]);
    }
    { // layer 0 from sparse features: 11 dense rows + 1 one-hot row of W0
      int t = t0 + rb + rl;
      float tv = times[b * TLEN + t];
      float vv = values[b * TLEN + t];
      int mm = meas[b * TLEN + t];
      float f[11];
#pragma unroll
      for (int i = 0; i < 5; ++i) { float s = tv * invts[i]; f[i] = sinf(s); f[5 + i] = cosf(s); }
      f[10] = vv;
      float4 a[8];
      const float* bp = b0 + cg * 32;
#pragma unroll
      for (int j = 0; j < 8; ++j) a[j] = *(const float4*)(bp + j * 4);
#pragma unroll
      for (int i = 0; i < 11; ++i) {
        const float* wr = W0 + i * 128 + cg * 32;
        float fi = f[i];
#pragma unroll
        for (int j = 0; j < 8; ++j) {
          float4 w = *(const float4*)(wr + j * 4);
          a[j].x = fmaf(fi, w.x, a[j].x); a[j].y = fmaf(fi, w.y, a[j].y);
          a[j].z = fmaf(fi, w.z, a[j].z); a[j].w = fmaf(fi, w.w, a[j].w);
        }
      }
      {
        const float* wr = W0 + (11 + mm) * 128 + cg * 32;
#pragma unroll
        for (int j = 0; j < 8; ++j) {
          float4 w = *(const float4*)(wr + j * 4);
          a[j].x += w.x; a[j].y += w.y; a[j].z += w.z; a[j].w += w.w;
        }
      }
#pragma unroll
      for (int j = 0; j < 8; ++j) {
        unsigned q0 = (unsigned)f2bf_rne(fmaxf(a[j].x, 0.f)) | ((unsigned)f2bf_rne(fmaxf(a[j].y, 0.f)) << 16);
        unsigned q1 = (unsigned)f2bf_rne(fmaxf(a[j].z, 0.f)) | ((unsigned)f2bf_rne(fmaxf(a[j].w, 0.f)) << 16);
        *(uint2*)(hA + rl * 136 + cg * 32 + j * 4) = make_uint2(q0, q1);
      }
    }
    __syncthreads();
    gemm64x128(W1, b1, hA, hB, tid); __syncthreads();
    gemm64x128(W2, b2, hB, hA, tid); __syncthreads();
    gemm64x128(W3, b3, hA, hB, tid); __syncthreads();
    // pacc[h][l] += e[r][h]*enc[r][l]; s[h] += e[r][h]
    for (int r = 0; r < 64; ++r) {
      float e0 = elds[r * 4 + hh0];
      float e1 = elds[r * 4 + hh0 + 2];
      float ev = bfbits2f(hB[r * 136 + ll]);
      pacc0 = fmaf(e0, ev, pacc0);
      pacc1 = fmaf(e1, ev, pacc1);
      sacc0 += e0; sacc1 += e1;
    }
    __syncthreads();
  }
  float* P = part + (b * NPART + c) * PART_STRIDE;
  if (tid < 4) P[tid] = mblk[tid];
  if (ll == 0) { P[4 + hh0] = sacc0; P[4 + hh0 + 2] = sacc1; }
  P[8 + hh0 * 128 + ll] = pacc0;
  P[8 + (hh0 + 2) * 128 + ll] = pacc1;
}

// ---------------- K4: combine partials, softmax-normalize, rho MLP, sigmoid ----------------
__global__ __launch_bounds__(256) void k_combine(
    const float* __restrict__ part,
    const float* __restrict__ rW0, const float* __restrict__ rb0,
    const float* __restrict__ rW1, const float* __restrict__ rb1,
    const float* __restrict__ rW2, const float* __restrict__ rb2,
    const float* __restrict__ rW3, const float* __restrict__ rb3,
    float* __restrict__ out) {
  __shared__ float mg[4], Ss[4], sc[36], agg[512], r1[128], r2[128], r3[128];
  int tid = threadIdx.x;
  int b = blockIdx.x;
  const float* P = part + b * NPART * PART_STRIDE;
  if (tid < 4) {
    float m = -1e30f;
    for (int p = 0; p < NPART; ++p) m = fmaxf(m, P[p * PART_STRIDE + tid]);
    mg[tid] = m;
  }
  __syncthreads();
  if (tid < 36) {
    int p = tid >> 2, h = tid & 3;
    sc[tid] = expf(P[p * PART_STRIDE + h] - mg[h]);
  }
  __syncthreads();
  if (tid < 4) {
    float s = 0.f;
    for (int p = 0; p < NPART; ++p) s += P[p * PART_STRIDE + 4 + tid] * sc[p * 4 + tid];
    Ss[tid] = s;
  }
  __syncthreads();
  for (int idx = tid; idx < 512; idx += 256) {
    int h = idx >> 7;
    float a = 0.f;
    for (int p = 0; p < NPART; ++p) a = fmaf(P[p * PART_STRIDE + 8 + idx], sc[p * 4 + h], a);
    agg[idx] = a / Ss[h];
  }
  __syncthreads();
  if (tid < 128) {
    float a = rb0[tid];
    for (int k = 0; k < 512; ++k) a = fmaf(agg[k], rW0[k * 128 + tid], a);
    r1[tid] = fmaxf(a, 0.f);
  }
  __syncthreads();
  if (tid < 128) {
    float a = rb1[tid];
    for (int k = 0; k < 128; ++k) a = fmaf(r1[k], rW1[k * 128 + tid], a);
    r2[tid] = fmaxf(a, 0.f);
  }
  __syncthreads();
  if (tid < 128) {
    float a = rb2[tid];
    for (int k = 0; k < 128; ++k) a = fmaf(r2[k], rW2[k * 128 + tid], a);
    r3[tid] = fmaxf(a, 0.f);
  }
  __syncthreads();
  if (tid == 0) {
    float a = rb3[0];
    for (int k = 0; k < 128; ++k) a = fmaf(r3[k], rW3[k], a);
    out[b] = 1.f / (1.f + expf(-a));
  }
}

extern "C" void kernel_launch(void* const* d_in, const int* in_sizes, int n_in,
                              void* d_out, int out_size, void* d_ws, size_t ws_size,
                              hipStream_t stream) {
  const float* demo   = (const float*)d_in[0];
  const float* times  = (const float*)d_in[1];
  const float* values = (const float*)d_in[2];
  const int*   meas   = (const int*)d_in[3];
  // d_in[4] segment_ids: static layout repeat(arange(64), 4097) — unused
  const float* tsc = (const float*)d_in[5];
  const float* dW1 = (const float*)d_in[6];
  const float* db1 = (const float*)d_in[7];
  const float* dW2 = (const float*)d_in[8];
  const float* db2 = (const float*)d_in[9];
  const float* pW0 = (const float*)d_in[10];
  const float* pb0 = (const float*)d_in[11];
  const float* pW1 = (const float*)d_in[12];
  const float* pb1 = (const float*)d_in[13];
  const float* pW2 = (const float*)d_in[14];
  const float* pb2 = (const float*)d_in[15];
  const float* pW3 = (const float*)d_in[16];
  const float* pb3 = (const float*)d_in[17];
  // d_in[18..23] psi weights: provably dead (per-segment-constant preattn shift
  // cancels exactly in segment softmax) — skipped
  const float* Wk  = (const float*)d_in[24];
  const float* Wq  = (const float*)d_in[25];
  const float* rW0 = (const float*)d_in[26];
  const float* rb0 = (const float*)d_in[27];
  const float* rW1 = (const float*)d_in[28];
  const float* rb1 = (const float*)d_in[29];
  const float* rW2 = (const float*)d_in[30];
  const float* rb2 = (const float*)d_in[31];
  const float* rW3 = (const float*)d_in[32];
  const float* rb3 = (const float*)d_in[33];
  float* ws = (float*)d_ws;
  float* partials = ws + OFF_PARTIALS;

  k_prep<<<1, 256, 0, stream>>>(demo, dW1, db1, dW2, db2, Wk, Wq, ws);
  k_demo<<<1, 256, 0, stream>>>(ws, pW0, pb0, pW1, pb1, pW2, pb2, pW3, pb3, partials);
  k_main<<<512, 256, 0, stream>>>(times, values, meas, tsc, ws,
                                  pW0, pb0, pW1, pb1, pW2, pb2, pW3, pb3, partials);
  k_combine<<<64, 256, 0, stream>>>(partials, rW0, rb0, rW1, rb1, rW2, rb2, rW3, rb3,
                                    (float*)d_out);
}

// Round 4
// 294.969 us; speedup vs baseline: 2.9331x; 2.9331x over previous
//
#include <hip/hip_runtime.h>
#include <hip/hip_bf16.h>
#include <math.h>

// All tensor inputs are float32; output is float32 (64 sigmoid values).
// Algebraic reductions vs reference:
//  - psi branch enters ONLY as a per-(segment,head) additive constant on
//    preattn -> cancels exactly in segment softmax -> skipped entirely.
//  - preattn = collected @ wq_eff, wq_eff[48,4] = W_k[:48]·W_q^T/8.
//  - collected = [10 pos | 1 value | 37 one-hot]; layer 0 input built
//    directly in LDS (bf16, K padded 48->64 with zeros).
// phi chain runs on MFMA (16x16x32 bf16); weights pre-transposed to bf16
// B-fragment-friendly layout Wt[n][k] by k_wprep, held in VGPRs per wave.

#define BSEG 64
#define TLEN 4096
#define NPART 9          // 8 main chunks + 1 demo partial per segment
#define PART_STRIDE 520  // m[4], s[4], pacc[4*128]

// ws layout (float offsets)
#define OFF_DEMO 0                 // demo_enc 64*48
#define OFF_WQ   3072              // wq_eff 48*4
#define OFF_WT   3264              // bf16 Wt: 128*64 + 3*128*128 = 57344 hw = 28672 floats
#define OFF_PARTIALS 31936         // 64*9*520 floats

typedef __attribute__((ext_vector_type(8))) short short8;
typedef __attribute__((ext_vector_type(4))) float f32x4;

static __device__ __forceinline__ float bfbits2f(unsigned v) { return __uint_as_float(v << 16); }
static __device__ __forceinline__ unsigned short f2bf_rne(float x) {
  unsigned u = __float_as_uint(x);
  unsigned r = (u + 0x7FFFu + ((u >> 16) & 1u)) >> 16;
  return (unsigned short)r;
}

// ---------------- K0: transpose weights to bf16 Wt[n][k] in ws ----------------
// Layer0: Wt0[128][64] (k 48..63 zero). Layers1-3: Wt[128][128].
__global__ __launch_bounds__(256) void k_wprep(
    const float* __restrict__ W0, const float* __restrict__ W1,
    const float* __restrict__ W2, const float* __restrict__ W3,
    float* __restrict__ ws) {
  unsigned short* wt = (unsigned short*)(ws + OFF_WT);
  int i = blockIdx.x * 256 + threadIdx.x;
  if (i >= 57344) return;
  float v;
  if (i < 8192) {
    int n = i >> 6, k = i & 63;
    v = (k < 48) ? W0[k * 128 + n] : 0.f;
  } else {
    int j = i - 8192;
    int l = j >> 14, r = j & 16383;
    int n = r >> 7, k = r & 127;
    const float* W = (l == 0) ? W1 : (l == 1) ? W2 : W3;
    v = W[k * 128 + n];
  }
  wt[i] = f2bf_rne(v);
}

// ---------------- K1: demo encoder + wq_eff ----------------
__global__ __launch_bounds__(256) void k_prep(
    const float* __restrict__ demo, const float* __restrict__ dW1, const float* __restrict__ db1,
    const float* __restrict__ dW2, const float* __restrict__ db2,
    const float* __restrict__ Wk, const float* __restrict__ Wq, float* __restrict__ ws) {
  __shared__ float dl[64 * 8];
  __shared__ float hd[64 * 128];
  int tid = threadIdx.x;
  for (int i = tid; i < 512; i += 256) dl[i] = demo[i];
  __syncthreads();
  for (int idx = tid; idx < 8192; idx += 256) {
    int r = idx >> 7, c = idx & 127;
    float a = db1[c];
#pragma unroll
    for (int i = 0; i < 8; ++i) a = fmaf(dl[r * 8 + i], dW1[i * 128 + c], a);
    hd[idx] = fmaxf(a, 0.f);
  }
  __syncthreads();
  for (int idx = tid; idx < 3072; idx += 256) {
    int r = idx / 48, c = idx % 48;
    float a = db2[c];
    for (int k = 0; k < 128; ++k) a = fmaf(hd[r * 128 + k], dW2[k * 48 + c], a);
    ws[OFF_DEMO + idx] = a;   // no relu on demo-encoder output
  }
  if (tid < 192) {
    int i = tid >> 2, h = tid & 3;
    float a = 0.f;
    for (int d = 0; d < 64; ++d) a = fmaf(Wk[i * 256 + h * 64 + d], Wq[h * 64 + d], a);
    ws[OFF_WQ + tid] = a * 0.125f;   // 1/sqrt(64)
  }
}

// ---------------- VALU GEMM core (k_demo only; 1 block, not hot) ----------
static __device__ __forceinline__ void gemm64x128(
    const float* __restrict__ W, const float* __restrict__ bias,
    const unsigned short* hin, unsigned short* hout, int tid) {
  const int ct = tid & 15, rt = tid >> 4;
  const int c0 = ct * 8, r0 = rt * 4;
  float acc[4][8];
  {
    float4 bv0 = *(const float4*)(bias + c0);
    float4 bv1 = *(const float4*)(bias + c0 + 4);
#pragma unroll
    for (int i = 0; i < 4; ++i) {
      acc[i][0] = bv0.x; acc[i][1] = bv0.y; acc[i][2] = bv0.z; acc[i][3] = bv0.w;
      acc[i][4] = bv1.x; acc[i][5] = bv1.y; acc[i][6] = bv1.z; acc[i][7] = bv1.w;
    }
  }
  for (int k4 = 0; k4 < 128; k4 += 4) {
    float hv[4][4];
#pragma unroll
    for (int i = 0; i < 4; ++i) {
      uint2 hw = *(const uint2*)(hin + (r0 + i) * 136 + k4);
      hv[i][0] = bfbits2f(hw.x & 0xFFFFu);
      hv[i][1] = __uint_as_float(hw.x & 0xFFFF0000u);
      hv[i][2] = bfbits2f(hw.y & 0xFFFFu);
      hv[i][3] = __uint_as_float(hw.y & 0xFFFF0000u);
    }
#pragma unroll
    for (int kk = 0; kk < 4; ++kk) {
      float4 w0 = *(const float4*)(W + (k4 + kk) * 128 + c0);
      float4 w1 = *(const float4*)(W + (k4 + kk) * 128 + c0 + 4);
      float wv[8] = {w0.x, w0.y, w0.z, w0.w, w1.x, w1.y, w1.z, w1.w};
#pragma unroll
      for (int i = 0; i < 4; ++i)
#pragma unroll
        for (int j = 0; j < 8; ++j)
          acc[i][j] = fmaf(hv[i][kk], wv[j], acc[i][j]);
    }
  }
#pragma unroll
  for (int i = 0; i < 4; ++i) {
    unsigned p0 = (unsigned)f2bf_rne(fmaxf(acc[i][0], 0.f)) | ((unsigned)f2bf_rne(fmaxf(acc[i][1], 0.f)) << 16);
    unsigned p1 = (unsigned)f2bf_rne(fmaxf(acc[i][2], 0.f)) | ((unsigned)f2bf_rne(fmaxf(acc[i][3], 0.f)) << 16);
    unsigned p2 = (unsigned)f2bf_rne(fmaxf(acc[i][4], 0.f)) | ((unsigned)f2bf_rne(fmaxf(acc[i][5], 0.f)) << 16);
    unsigned p3 = (unsigned)f2bf_rne(fmaxf(acc[i][6], 0.f)) | ((unsigned)f2bf_rne(fmaxf(acc[i][7], 0.f)) << 16);
    *(uint4*)(hout + (r0 + i) * 136 + c0) = make_uint4(p0, p1, p2, p3);
  }
}

// ---------------- K2: demo rows (row 0 of each segment) -> partial p=8 ----------------
__global__ __launch_bounds__(256) void k_demo(
    const float* __restrict__ ws,
    const float* __restrict__ W0, const float* __restrict__ b0,
    const float* __restrict__ W1, const float* __restrict__ b1,
    const float* __restrict__ W2, const float* __restrict__ b2,
    const float* __restrict__ W3, const float* __restrict__ b3,
    float* __restrict__ part) {
  __shared__ float x[64 * 48];
  __shared__ __align__(16) unsigned short hA[64 * 136];
  __shared__ __align__(16) unsigned short hB[64 * 136];
  __shared__ float pre[256];
  int tid = threadIdx.x;
  for (int i = tid; i < 3072; i += 256) x[i] = ws[OFF_DEMO + i];
  __syncthreads();
  {
    int r = tid >> 2, h = tid & 3;
    float a = 0.f;
    for (int i = 0; i < 48; ++i) a = fmaf(x[r * 48 + i], ws[OFF_WQ + i * 4 + h], a);
    pre[tid] = a;
  }
  {
    int rl = tid & 63, cg = tid >> 6;
    float4 a[8];
    const float* bp = b0 + cg * 32;
#pragma unroll
    for (int j = 0; j < 8; ++j) a[j] = *(const float4*)(bp + j * 4);
    for (int i = 0; i < 48; ++i) {
      float xi = x[rl * 48 + i];
      const float* wr = W0 + i * 128 + cg * 32;
#pragma unroll
      for (int j = 0; j < 8; ++j) {
        float4 w = *(const float4*)(wr + j * 4);
        a[j].x = fmaf(xi, w.x, a[j].x); a[j].y = fmaf(xi, w.y, a[j].y);
        a[j].z = fmaf(xi, w.z, a[j].z); a[j].w = fmaf(xi, w.w, a[j].w);
      }
    }
#pragma unroll
    for (int j = 0; j < 8; ++j) {
      unsigned q0 = (unsigned)f2bf_rne(fmaxf(a[j].x, 0.f)) | ((unsigned)f2bf_rne(fmaxf(a[j].y, 0.f)) << 16);
      unsigned q1 = (unsigned)f2bf_rne(fmaxf(a[j].z, 0.f)) | ((unsigned)f2bf_rne(fmaxf(a[j].w, 0.f)) << 16);
      *(uint2*)(hA + rl * 136 + cg * 32 + j * 4) = make_uint2(q0, q1);
    }
  }
  __syncthreads();
  gemm64x128(W1, b1, hA, hB, tid); __syncthreads();
  gemm64x128(W2, b2, hB, hA, tid); __syncthreads();
  gemm64x128(W3, b3, hA, hB, tid); __syncthreads();
  {
    int r = tid >> 2, h = tid & 3;
    float* P = part + (r * NPART + 8) * PART_STRIDE;
    P[h] = pre[tid];
    P[4 + h] = 1.f;
  }
  for (int i = tid; i < 64 * 512; i += 256) {
    int r = i >> 9, rem = i & 511, l = rem & 127;
    part[(r * NPART + 8) * PART_STRIDE + 8 + rem] = bfbits2f(hB[r * 136 + l]);
  }
}

// ---------------- MFMA layer: [64x128] = relu([64x128] @ W + b), K=128 ----------
// A from LDS (stride 136 hw), B-frags in VGPRs (wave owns cols n0..n0+31).
static __device__ __forceinline__ void mfma_layer(
    const unsigned short* hin, unsigned short* hout,
    const short8 (&Bf)[2][4], const float (&bias)[2],
    int l16, int quad, int n0) {
#pragma unroll
  for (int mt = 0; mt < 4; ++mt) {
    short8 A[4];
#pragma unroll
    for (int s = 0; s < 4; ++s)
      A[s] = *(const short8*)(hin + (mt * 16 + l16) * 136 + s * 32 + quad * 8);
#pragma unroll
    for (int t = 0; t < 2; ++t) {
      f32x4 acc = {bias[t], bias[t], bias[t], bias[t]};
#pragma unroll
      for (int s = 0; s < 4; ++s)
        acc = __builtin_amdgcn_mfma_f32_16x16x32_bf16(A[s], Bf[t][s], acc, 0, 0, 0);
      int col = n0 + t * 16 + l16;
#pragma unroll
      for (int j = 0; j < 4; ++j)
        hout[(mt * 16 + quad * 4 + j) * 136 + col] = f2bf_rne(fmaxf(acc[j], 0.f));
    }
  }
}

// ---------------- K3: main — 64 segments x 8 chunks of 512 time rows ----------------
__global__ __launch_bounds__(256, 2) void k_main(
    const float* __restrict__ times, const float* __restrict__ values,
    const int* __restrict__ meas, const float* __restrict__ tsc,
    const float* __restrict__ ws,
    const float* __restrict__ b0g, const float* __restrict__ b1g,
    const float* __restrict__ b2g, const float* __restrict__ b3g,
    float* __restrict__ part) {
  __shared__ __align__(16) unsigned short hA[64 * 136];
  __shared__ __align__(16) unsigned short hB[64 * 136];
  __shared__ __align__(16) unsigned short c0[64 * 72];
  __shared__ float preb[512 * 4];
  __shared__ float maxred[256 * 4];
  __shared__ float elds[256];
  __shared__ float wql[192];
  __shared__ float mblk[4];
  int tid = threadIdx.x;
  int b = blockIdx.x >> 3, c = blockIdx.x & 7;
  int t0 = c << 9;
  const int lane = tid & 63, wv = tid >> 6, quad = lane >> 4, l16 = lane & 15;
  const int n0 = wv * 32;

  // persistent B-fragments + biases (once per block)
  const unsigned short* wt = (const unsigned short*)(ws + OFF_WT);
  short8 B0[2][2], B1[2][4], B2[2][4], B3[2][4];
  float bias0[2], bias1[2], bias2[2], bias3[2];
#pragma unroll
  for (int t = 0; t < 2; ++t) {
    int n = n0 + t * 16 + l16;
    bias0[t] = b0g[n]; bias1[t] = b1g[n]; bias2[t] = b2g[n]; bias3[t] = b3g[n];
#pragma unroll
    for (int s = 0; s < 2; ++s)
      B0[t][s] = *(const short8*)(wt + n * 64 + s * 32 + quad * 8);
#pragma unroll
    for (int s = 0; s < 4; ++s) {
      B1[t][s] = *(const short8*)(wt + 8192  + n * 128 + s * 32 + quad * 8);
      B2[t][s] = *(const short8*)(wt + 24576 + n * 128 + s * 32 + quad * 8);
      B3[t][s] = *(const short8*)(wt + 40960 + n * 128 + s * 32 + quad * 8);
    }
  }

  if (tid < 192) wql[tid] = ws[OFF_WQ + tid];
  float invts[5];
#pragma unroll
  for (int i = 0; i < 5; ++i) invts[i] = 1.f / tsc[i];
  __syncthreads();

  // ---- phase A: preattn + block max over this chunk's 512 rows ----
  float mloc[4] = {-1e30f, -1e30f, -1e30f, -1e30f};
  for (int rr = 0; rr < 2; ++rr) {
    int r = tid + rr * 256;
    int t = t0 + r;
    float tv = times[b * TLEN + t];
    float vvv = values[b * TLEN + t];
    int mm = meas[b * TLEN + t];
    float f[11];
#pragma unroll
    for (int i = 0; i < 5; ++i) { float s = tv * invts[i]; f[i] = sinf(s); f[5 + i] = cosf(s); }
    f[10] = vvv;
#pragma unroll
    for (int h = 0; h < 4; ++h) {
      float a = wql[(11 + mm) * 4 + h];
#pragma unroll
      for (int i = 0; i < 11; ++i) a = fmaf(f[i], wql[i * 4 + h], a);
      preb[r * 4 + h] = a;
      mloc[h] = fmaxf(mloc[h], a);
    }
  }
#pragma unroll
  for (int h = 0; h < 4; ++h) maxred[tid * 4 + h] = mloc[h];
  __syncthreads();
  for (int s = 128; s > 0; s >>= 1) {
    if (tid < s) {
#pragma unroll
      for (int h = 0; h < 4; ++h)
        maxred[tid * 4 + h] = fmaxf(maxred[tid * 4 + h], maxred[(tid + s) * 4 + h]);
    }
    __syncthreads();
  }
  if (tid < 4) mblk[tid] = maxred[tid];
  __syncthreads();

  // ---- phase B: 8 tiles of 64 rows: MFMA phi chain + weighted accumulation ----
  float pacc0 = 0.f, pacc1 = 0.f, sacc0 = 0.f, sacc1 = 0.f;
  const int hh0 = tid >> 7, ll = tid & 127;
  for (int tile = 0; tile < 8; ++tile) {
    int rb = tile << 6;
    elds[tid] = expf(preb[(rb + (tid >> 2)) * 4 + (tid & 3)] - mblk[tid & 3]);
    { // build collected tile c0[64][72] bf16 (k 0..47 features, 48..63 zero)
      int r = tid >> 2, cs = tid & 3;
      int t = t0 + rb + r;
      unsigned short seg[16];
#pragma unroll
      for (int i = 0; i < 16; ++i) seg[i] = 0;
      if (cs == 0) {
        float tv = times[b * TLEN + t];
        float vvv = values[b * TLEN + t];
#pragma unroll
        for (int i = 0; i < 5; ++i) {
          float s = tv * invts[i];
          seg[i] = f2bf_rne(sinf(s));
          seg[5 + i] = f2bf_rne(cosf(s));
        }
        seg[10] = f2bf_rne(vvv);
      }
      int kk = 11 + meas[b * TLEN + t];
      if ((kk >> 4) == cs) seg[kk & 15] = 0x3F80;   // bf16(1.0)
      unsigned u[8];
#pragma unroll
      for (int i = 0; i < 8; ++i) u[i] = (unsigned)seg[2 * i] | ((unsigned)seg[2 * i + 1] << 16);
      uint4* dst = (uint4*)(c0 + r * 72 + cs * 16);
      dst[0] = make_uint4(u[0], u[1], u[2], u[3]);
      dst[1] = make_uint4(u[4], u[5], u[6], u[7]);
    }
    __syncthreads();
    // layer 0: c0 (K=64, zero-padded) -> hA
#pragma unroll
    for (int mt = 0; mt < 4; ++mt) {
      short8 A0[2];
#pragma unroll
      for (int s = 0; s < 2; ++s)
        A0[s] = *(const short8*)(c0 + (mt * 16 + l16) * 72 + s * 32 + quad * 8);
#pragma unroll
      for (int t = 0; t < 2; ++t) {
        f32x4 acc = {bias0[t], bias0[t], bias0[t], bias0[t]};
        acc = __builtin_amdgcn_mfma_f32_16x16x32_bf16(A0[0], B0[t][0], acc, 0, 0, 0);
        acc = __builtin_amdgcn_mfma_f32_16x16x32_bf16(A0[1], B0[t][1], acc, 0, 0, 0);
        int col = n0 + t * 16 + l16;
#pragma unroll
        for (int j = 0; j < 4; ++j)
          hA[(mt * 16 + quad * 4 + j) * 136 + col] = f2bf_rne(fmaxf(acc[j], 0.f));
      }
    }
    __syncthreads();
    mfma_layer(hA, hB, B1, bias1, l16, quad, n0); __syncthreads();
    mfma_layer(hB, hA, B2, bias2, l16, quad, n0); __syncthreads();
    mfma_layer(hA, hB, B3, bias3, l16, quad, n0); __syncthreads();
    // pacc[h][l] += e[r][h]*enc[r][l]; s[h] += e[r][h]
    for (int r = 0; r < 64; ++r) {
      float e0 = elds[r * 4 + hh0];
      float e1 = elds[r * 4 + hh0 + 2];
      float ev = bfbits2f(hB[r * 136 + ll]);
      pacc0 = fmaf(e0, ev, pacc0);
      pacc1 = fmaf(e1, ev, pacc1);
      sacc0 += e0; sacc1 += e1;
    }
    __syncthreads();
  }
  float* P = part + (b * NPART + c) * PART_STRIDE;
  if (tid < 4) P[tid] = mblk[tid];
  if (ll == 0) { P[4 + hh0] = sacc0; P[4 + hh0 + 2] = sacc1; }
  P[8 + hh0 * 128 + ll] = pacc0;
  P[8 + (hh0 + 2) * 128 + ll] = pacc1;
}

// ---------------- K4: combine partials, softmax-normalize, rho MLP, sigmoid ----------------
__global__ __launch_bounds__(256) void k_combine(
    const float* __restrict__ part,
    const float* __restrict__ rW0, const float* __restrict__ rb0,
    const float* __restrict__ rW1, const float* __restrict__ rb1,
    const float* __restrict__ rW2, const float* __restrict__ rb2,
    const float* __restrict__ rW3, const float* __restrict__ rb3,
    float* __restrict__ out) {
  __shared__ float mg[4], Ss[4], sc[36], agg[512], r1[128], r2[128], r3[128];
  int tid = threadIdx.x;
  int b = blockIdx.x;
  const float* P = part + b * NPART * PART_STRIDE;
  if (tid < 4) {
    float m = -1e30f;
    for (int p = 0; p < NPART; ++p) m = fmaxf(m, P[p * PART_STRIDE + tid]);
    mg[tid] = m;
  }
  __syncthreads();
  if (tid < 36) {
    int p = tid >> 2, h = tid & 3;
    sc[tid] = expf(P[p * PART_STRIDE + h] - mg[h]);
  }
  __syncthreads();
  if (tid < 4) {
    float s = 0.f;
    for (int p = 0; p < NPART; ++p) s += P[p * PART_STRIDE + 4 + tid] * sc[p * 4 + tid];
    Ss[tid] = s;
  }
  __syncthreads();
  for (int idx = tid; idx < 512; idx += 256) {
    int h = idx >> 7;
    float a = 0.f;
    for (int p = 0; p < NPART; ++p) a = fmaf(P[p * PART_STRIDE + 8 + idx], sc[p * 4 + h], a);
    agg[idx] = a / Ss[h];
  }
  __syncthreads();
  if (tid < 128) {
    float a = rb0[tid];
    for (int k = 0; k < 512; ++k) a = fmaf(agg[k], rW0[k * 128 + tid], a);
    r1[tid] = fmaxf(a, 0.f);
  }
  __syncthreads();
  if (tid < 128) {
    float a = rb1[tid];
    for (int k = 0; k < 128; ++k) a = fmaf(r1[k], rW1[k * 128 + tid], a);
    r2[tid] = fmaxf(a, 0.f);
  }
  __syncthreads();
  if (tid < 128) {
    float a = rb2[tid];
    for (int k = 0; k < 128; ++k) a = fmaf(r2[k], rW2[k * 128 + tid], a);
    r3[tid] = fmaxf(a, 0.f);
  }
  __syncthreads();
  if (tid == 0) {
    float a = rb3[0];
    for (int k = 0; k < 128; ++k) a = fmaf(r3[k], rW3[k], a);
    out[b] = 1.f / (1.f + expf(-a));
  }
}

extern "C" void kernel_launch(void* const* d_in, const int* in_sizes, int n_in,
                              void* d_out, int out_size, void* d_ws, size_t ws_size,
                              hipStream_t stream) {
  const float* demo   = (const float*)d_in[0];
  const float* times  = (const float*)d_in[1];
  const float* values = (const float*)d_in[2];
  const int*   meas   = (const int*)d_in[3];
  // d_in[4] segment_ids: static layout repeat(arange(64), 4097) — unused
  const float* tsc = (const float*)d_in[5];
  const float* dW1 = (const float*)d_in[6];
  const float* db1 = (const float*)d_in[7];
  const float* dW2 = (const float*)d_in[8];
  const float* db2 = (const float*)d_in[9];
  const float* pW0 = (const float*)d_in[10];
  const float* pb0 = (const float*)d_in[11];
  const float* pW1 = (const float*)d_in[12];
  const float* pb1 = (const float*)d_in[13];
  const float* pW2 = (const float*)d_in[14];
  const float* pb2 = (const float*)d_in[15];
  const float* pW3 = (const float*)d_in[16];
  const float* pb3 = (const float*)d_in[17];
  // d_in[18..23] psi weights: provably dead — skipped
  const float* Wk  = (const float*)d_in[24];
  const float* Wq  = (const float*)d_in[25];
  const float* rW0 = (const float*)d_in[26];
  const float* rb0 = (const float*)d_in[27];
  const float* rW1 = (const float*)d_in[28];
  const float* rb1 = (const float*)d_in[29];
  const float* rW2 = (const float*)d_in[30];
  const float* rb2 = (const float*)d_in[31];
  const float* rW3 = (const float*)d_in[32];
  const float* rb3 = (const float*)d_in[33];
  float* ws = (float*)d_ws;
  float* partials = ws + OFF_PARTIALS;

  k_wprep<<<224, 256, 0, stream>>>(pW0, pW1, pW2, pW3, ws);
  k_prep<<<1, 256, 0, stream>>>(demo, dW1, db1, dW2, db2, Wk, Wq, ws);
  k_demo<<<1, 256, 0, stream>>>(ws, pW0, pb0, pW1, pb1, pW2, pb2, pW3, pb3, partials);
  k_main<<<512, 256, 0, stream>>>(times, values, meas, tsc, ws,
                                  pb0, pb1, pb2, pb3, partials);
  k_combine<<<64, 256, 0, stream>>>(partials, rW0, rb0, rW1, rb1, rW2, rb2, rW3, rb3,
                                    (float*)d_out);
}

// Round 5
// 281.804 us; speedup vs baseline: 3.0701x; 1.0467x over previous
//
#include <hip/hip_runtime.h>
#include <hip/hip_bf16.h>
#include <math.h>

// All tensor inputs float32; output float32 (64 sigmoid values).
// Algebraic reductions vs reference:
//  - psi branch enters ONLY as a per-(segment,head) additive constant on
//    preattn -> cancels exactly in segment softmax -> skipped entirely.
//  - preattn = collected @ wq_eff, wq_eff[48,4] = W_k[:48]·W_q^T/8.
//  - collected = [10 pos | 1 value | 37 one-hot]; layer-0 input built
//    directly in LDS (bf16, K padded 48->64 with zeros).
// phi chain on MFMA 16x16x32 bf16; weights pre-transposed bf16 Wt[n][k],
// held in VGPRs per wave. Demo rows = one extra 64-row tile (block 512).

#define BSEG 64
#define TLEN 4096
#define NPART 9          // 8 main chunks + 1 demo partial per segment
#define PART_STRIDE 520  // m[4], s[4], pacc[4*128]

// ws layout (float offsets)
#define OFF_DEMO 0                 // demo_enc 64*48
#define OFF_WQ   3072              // wq_eff 48*4
#define OFF_WT   3264              // bf16 Wt: 128*64 + 3*128*128 = 57344 hw
#define OFF_PARTIALS 31936         // 64*9*520 floats

typedef __attribute__((ext_vector_type(8))) short short8;
typedef __attribute__((ext_vector_type(4))) float f32x4;

static __device__ __forceinline__ float bfbits2f(unsigned v) { return __uint_as_float(v << 16); }
static __device__ __forceinline__ unsigned short f2bf_rne(float x) {
  unsigned u = __float_as_uint(x);
  unsigned r = (u + 0x7FFFu + ((u >> 16) & 1u)) >> 16;
  return (unsigned short)r;
}

// ---------------- K_prep: weight transpose + wq_eff + demo encoder ----------------
// blocks 0..223: transpose phi weights to bf16 Wt[n][k] (layer0 K-padded to 64)
// block 224: wq_eff ; block 225: demo encoder (dW2 staged in LDS)
__global__ __launch_bounds__(256) void k_prep(
    const float* __restrict__ demo, const float* __restrict__ dW1, const float* __restrict__ db1,
    const float* __restrict__ dW2, const float* __restrict__ db2,
    const float* __restrict__ Wk, const float* __restrict__ Wq,
    const float* __restrict__ W0, const float* __restrict__ W1,
    const float* __restrict__ W2, const float* __restrict__ W3,
    float* __restrict__ ws) {
  __shared__ float dl[512];
  __shared__ float hd[8192];
  __shared__ float w2[6144];
  int bid = blockIdx.x, tid = threadIdx.x;
  if (bid < 224) {
    unsigned short* wt = (unsigned short*)(ws + OFF_WT);
    int i = bid * 256 + tid;
    float v;
    if (i < 8192) {
      int n = i >> 6, k = i & 63;
      v = (k < 48) ? W0[k * 128 + n] : 0.f;
    } else {
      int j = i - 8192;
      int l = j >> 14, r = j & 16383;
      int n = r >> 7, k = r & 127;
      const float* W = (l == 0) ? W1 : (l == 1) ? W2 : W3;
      v = W[k * 128 + n];
    }
    wt[i] = f2bf_rne(v);
    return;
  }
  if (bid == 224) {
    if (tid < 192) {
      int i = tid >> 2, h = tid & 3;
      float a = 0.f;
      for (int d = 0; d < 64; ++d) a = fmaf(Wk[i * 256 + h * 64 + d], Wq[h * 64 + d], a);
      ws[OFF_WQ + tid] = a * 0.125f;   // 1/sqrt(64)
    }
    return;
  }
  // bid == 225: demo encoder -> ws[OFF_DEMO]
  for (int i = tid; i < 512; i += 256) dl[i] = demo[i];
  for (int i = tid; i < 6144; i += 256) w2[i] = dW2[i];
  __syncthreads();
  for (int idx = tid; idx < 8192; idx += 256) {
    int r = idx >> 7, c = idx & 127;
    float a = db1[c];
#pragma unroll
    for (int i = 0; i < 8; ++i) a = fmaf(dl[r * 8 + i], dW1[i * 128 + c], a);
    hd[idx] = fmaxf(a, 0.f);
  }
  __syncthreads();
  for (int idx = tid; idx < 3072; idx += 256) {
    int r = idx / 48, c = idx % 48;
    float a = db2[c];
    for (int k = 0; k < 128; ++k) a = fmaf(hd[r * 128 + k], w2[k * 48 + c], a);
    ws[OFF_DEMO + idx] = a;   // no relu on demo-encoder output
  }
}

// ---------------- MFMA layer helpers ----------------
// store path: [64x128] = relu(in @ W + b) -> hout (stride 136 hw)
static __device__ __forceinline__ void mfma_layer(
    const unsigned short* hin, unsigned short* hout,
    const short8 (&Bf)[2][4], const float (&bias)[2],
    int l16, int quad, int n0) {
#pragma unroll
  for (int mt = 0; mt < 4; ++mt) {
    short8 A[4];
#pragma unroll
    for (int s = 0; s < 4; ++s)
      A[s] = *(const short8*)(hin + (mt * 16 + l16) * 136 + s * 32 + quad * 8);
#pragma unroll
    for (int t = 0; t < 2; ++t) {
      f32x4 acc = {bias[t], bias[t], bias[t], bias[t]};
#pragma unroll
      for (int s = 0; s < 4; ++s)
        acc = __builtin_amdgcn_mfma_f32_16x16x32_bf16(A[s], Bf[t][s], acc, 0, 0, 0);
      int col = n0 + t * 16 + l16;
#pragma unroll
      for (int j = 0; j < 4; ++j)
        hout[(mt * 16 + quad * 4 + j) * 136 + col] = f2bf_rne(fmaxf(acc[j], 0.f));
    }
  }
}
// layer 0: input c0 (stride 72 hw, K=64 zero-padded)
static __device__ __forceinline__ void mfma_layer0(
    const unsigned short* cin, unsigned short* hout,
    const short8 (&B0)[2][2], const float (&bias0)[2],
    int l16, int quad, int n0) {
#pragma unroll
  for (int mt = 0; mt < 4; ++mt) {
    short8 A0[2];
#pragma unroll
    for (int s = 0; s < 2; ++s)
      A0[s] = *(const short8*)(cin + (mt * 16 + l16) * 72 + s * 32 + quad * 8);
#pragma unroll
    for (int t = 0; t < 2; ++t) {
      f32x4 acc = {bias0[t], bias0[t], bias0[t], bias0[t]};
      acc = __builtin_amdgcn_mfma_f32_16x16x32_bf16(A0[0], B0[t][0], acc, 0, 0, 0);
      acc = __builtin_amdgcn_mfma_f32_16x16x32_bf16(A0[1], B0[t][1], acc, 0, 0, 0);
      int col = n0 + t * 16 + l16;
#pragma unroll
      for (int j = 0; j < 4; ++j)
        hout[(mt * 16 + quad * 4 + j) * 136 + col] = f2bf_rne(fmaxf(acc[j], 0.f));
    }
  }
}

// ---------------- K_main: blocks 0..511 = 64 segs x 8 chunks; block 512 = demo tile ----
__global__ __launch_bounds__(256, 3) void k_main(
    const float* __restrict__ times, const float* __restrict__ values,
    const int* __restrict__ meas, const float* __restrict__ tsc,
    const float* __restrict__ ws,
    const float* __restrict__ b0g, const float* __restrict__ b1g,
    const float* __restrict__ b2g, const float* __restrict__ b3g,
    float* __restrict__ part) {
  __shared__ __align__(16) unsigned short hA[64 * 136];
  __shared__ __align__(16) unsigned short hB[64 * 136];   // also c0 area (stride 72)
  __shared__ __align__(16) float preb[512 * 4];           // pre, then e in place
  __shared__ float wql[192];
  __shared__ float mred[16];
  __shared__ float mblk[4];
  int tid = threadIdx.x;
  const int lane = tid & 63, wv = tid >> 6, quad = lane >> 4, l16 = lane & 15;
  const int n0 = wv * 32;

  // persistent B-fragments + biases (once per block)
  const unsigned short* wt = (const unsigned short*)(ws + OFF_WT);
  short8 B0[2][2], B1[2][4], B2[2][4], B3[2][4];
  float bias0[2], bias1[2], bias2[2], bias3[2];
#pragma unroll
  for (int t = 0; t < 2; ++t) {
    int n = n0 + t * 16 + l16;
    bias0[t] = b0g[n]; bias1[t] = b1g[n]; bias2[t] = b2g[n]; bias3[t] = b3g[n];
#pragma unroll
    for (int s = 0; s < 2; ++s)
      B0[t][s] = *(const short8*)(wt + n * 64 + s * 32 + quad * 8);
#pragma unroll
    for (int s = 0; s < 4; ++s) {
      B1[t][s] = *(const short8*)(wt + 8192  + n * 128 + s * 32 + quad * 8);
      B2[t][s] = *(const short8*)(wt + 24576 + n * 128 + s * 32 + quad * 8);
      B3[t][s] = *(const short8*)(wt + 40960 + n * 128 + s * 32 + quad * 8);
    }
  }
  if (tid < 192) wql[tid] = ws[OFF_WQ + tid];
  __syncthreads();

  if (blockIdx.x == 512) {
    // ---- demo tile: 64 demo_enc rows through the same MFMA chain ----
    {
      int r = tid >> 2, cs = tid & 3;
      unsigned short seg[16];
#pragma unroll
      for (int i = 0; i < 16; ++i) seg[i] = 0;
      if (cs < 3)
#pragma unroll
        for (int i = 0; i < 16; ++i) seg[i] = f2bf_rne(ws[OFF_DEMO + r * 48 + cs * 16 + i]);
      unsigned u[8];
#pragma unroll
      for (int i = 0; i < 8; ++i) u[i] = (unsigned)seg[2 * i] | ((unsigned)seg[2 * i + 1] << 16);
      uint4* dst = (uint4*)(hB + r * 72 + cs * 16);
      dst[0] = make_uint4(u[0], u[1], u[2], u[3]);
      dst[1] = make_uint4(u[4], u[5], u[6], u[7]);
    }
    float pre;
    {
      int r = tid >> 2, h = tid & 3;
      float a = 0.f;
      for (int i = 0; i < 48; ++i) a = fmaf(ws[OFF_DEMO + r * 48 + i], wql[i * 4 + h], a);
      pre = a;
    }
    __syncthreads();
    mfma_layer0(hB, hA, B0, bias0, l16, quad, n0); __syncthreads();
    mfma_layer(hA, hB, B1, bias1, l16, quad, n0); __syncthreads();
    mfma_layer(hB, hA, B2, bias2, l16, quad, n0); __syncthreads();
    mfma_layer(hA, hB, B3, bias3, l16, quad, n0); __syncthreads();
    {
      int r = tid >> 2, h = tid & 3;
      float* P = part + (r * NPART + 8) * PART_STRIDE;
      P[h] = pre;
      P[4 + h] = 1.f;
    }
    for (int i = tid; i < 64 * 512; i += 256) {
      int r = i >> 9, rem = i & 511, l = rem & 127;
      part[(r * NPART + 8) * PART_STRIDE + 8 + rem] = bfbits2f(hB[r * 136 + l]);
    }
    return;
  }

  int b = blockIdx.x >> 3, c = blockIdx.x & 7;
  int t0 = c << 9;
  float invts[5];
#pragma unroll
  for (int i = 0; i < 5; ++i) invts[i] = 1.f / tsc[i];

  // ---- phase A: preattn + block max (shuffle) + e in place ----
  float mloc[4] = {-1e30f, -1e30f, -1e30f, -1e30f};
  for (int rr = 0; rr < 2; ++rr) {
    int r = tid + rr * 256;
    int t = t0 + r;
    float tv = times[b * TLEN + t];
    float vvv = values[b * TLEN + t];
    int mm = meas[b * TLEN + t];
    float f[11];
#pragma unroll
    for (int i = 0; i < 5; ++i) { float s = tv * invts[i]; f[i] = sinf(s); f[5 + i] = cosf(s); }
    f[10] = vvv;
#pragma unroll
    for (int h = 0; h < 4; ++h) {
      float a = wql[(11 + mm) * 4 + h];
#pragma unroll
      for (int i = 0; i < 11; ++i) a = fmaf(f[i], wql[i * 4 + h], a);
      preb[r * 4 + h] = a;
      mloc[h] = fmaxf(mloc[h], a);
    }
  }
#pragma unroll
  for (int off = 32; off > 0; off >>= 1)
#pragma unroll
    for (int h = 0; h < 4; ++h) mloc[h] = fmaxf(mloc[h], __shfl_xor(mloc[h], off, 64));
  if (lane == 0)
#pragma unroll
    for (int h = 0; h < 4; ++h) mred[wv * 4 + h] = mloc[h];
  __syncthreads();
  if (tid < 4)
    mblk[tid] = fmaxf(fmaxf(mred[tid], mred[4 + tid]), fmaxf(mred[8 + tid], mred[12 + tid]));
  __syncthreads();
  for (int i = tid; i < 2048; i += 256) preb[i] = expf(preb[i] - mblk[i & 3]);
  __syncthreads();

  // ---- phase B: 8 tiles of 64 rows ----
  float pacc[2][4] = {{0.f, 0.f, 0.f, 0.f}, {0.f, 0.f, 0.f, 0.f}};
  for (int tile = 0; tile < 8; ++tile) {
    int rb = tile << 6;
    { // build collected c0 into hB (stride 72): k 0..47 features, 48..63 zero
      int r = tid >> 2, cs = tid & 3;
      int t = t0 + rb + r;
      unsigned short seg[16];
#pragma unroll
      for (int i = 0; i < 16; ++i) seg[i] = 0;
      if (cs == 0) {
        float tv = times[b * TLEN + t];
        float vvv = values[b * TLEN + t];
#pragma unroll
        for (int i = 0; i < 5; ++i) {
          float s = tv * invts[i];
          seg[i] = f2bf_rne(sinf(s));
          seg[5 + i] = f2bf_rne(cosf(s));
        }
        seg[10] = f2bf_rne(vvv);
      }
      int kk = 11 + meas[b * TLEN + t];
      if ((kk >> 4) == cs) seg[kk & 15] = 0x3F80;   // bf16(1.0)
      unsigned u[8];
#pragma unroll
      for (int i = 0; i < 8; ++i) u[i] = (unsigned)seg[2 * i] | ((unsigned)seg[2 * i + 1] << 16);
      uint4* dst = (uint4*)(hB + r * 72 + cs * 16);
      dst[0] = make_uint4(u[0], u[1], u[2], u[3]);
      dst[1] = make_uint4(u[4], u[5], u[6], u[7]);
    }
    __syncthreads();
    mfma_layer0(hB, hA, B0, bias0, l16, quad, n0); __syncthreads();
    mfma_layer(hA, hB, B1, bias1, l16, quad, n0); __syncthreads();
    mfma_layer(hB, hA, B2, bias2, l16, quad, n0); __syncthreads();
    // L3: register epilogue — acc stays in VGPRs, fold Sum e*enc directly
#pragma unroll
    for (int mt = 0; mt < 4; ++mt) {
      short8 A[4];
#pragma unroll
      for (int s = 0; s < 4; ++s)
        A[s] = *(const short8*)(hA + (mt * 16 + l16) * 136 + s * 32 + quad * 8);
      f32x4 acc0 = {bias3[0], bias3[0], bias3[0], bias3[0]};
      f32x4 acc1 = {bias3[1], bias3[1], bias3[1], bias3[1]};
#pragma unroll
      for (int s = 0; s < 4; ++s) {
        acc0 = __builtin_amdgcn_mfma_f32_16x16x32_bf16(A[s], B3[0][s], acc0, 0, 0, 0);
        acc1 = __builtin_amdgcn_mfma_f32_16x16x32_bf16(A[s], B3[1][s], acc1, 0, 0, 0);
      }
#pragma unroll
      for (int j = 0; j < 4; ++j) {
        int row = rb + mt * 16 + quad * 4 + j;
        float4 e4 = *(const float4*)(preb + row * 4);   // broadcast across l16
        float v0 = fmaxf(acc0[j], 0.f), v1 = fmaxf(acc1[j], 0.f);
        pacc[0][0] = fmaf(v0, e4.x, pacc[0][0]);
        pacc[0][1] = fmaf(v0, e4.y, pacc[0][1]);
        pacc[0][2] = fmaf(v0, e4.z, pacc[0][2]);
        pacc[0][3] = fmaf(v0, e4.w, pacc[0][3]);
        pacc[1][0] = fmaf(v1, e4.x, pacc[1][0]);
        pacc[1][1] = fmaf(v1, e4.y, pacc[1][1]);
        pacc[1][2] = fmaf(v1, e4.z, pacc[1][2]);
        pacc[1][3] = fmaf(v1, e4.w, pacc[1][3]);
      }
    }
    __syncthreads();
  }
  // reduce pacc across quads (lanes l, l^16, l^32, l^48 share a column)
#pragma unroll
  for (int t = 0; t < 2; ++t)
#pragma unroll
    for (int h = 0; h < 4; ++h) {
      float v = pacc[t][h];
      v += __shfl_xor(v, 16, 64);
      v += __shfl_xor(v, 32, 64);
      pacc[t][h] = v;
    }
  float* P = part + (b * NPART + c) * PART_STRIDE;
  if (tid < 4) P[tid] = mblk[tid];
  { // s[h] = sum over 512 rows of e
    float s4[4];
#pragma unroll
    for (int h = 0; h < 4; ++h) s4[h] = preb[tid * 4 + h] + preb[(tid + 256) * 4 + h];
#pragma unroll
    for (int off = 32; off > 0; off >>= 1)
#pragma unroll
      for (int h = 0; h < 4; ++h) s4[h] += __shfl_xor(s4[h], off, 64);
    if (lane == 0)
#pragma unroll
      for (int h = 0; h < 4; ++h) mred[wv * 4 + h] = s4[h];
    __syncthreads();
    if (tid < 4) P[4 + tid] = mred[tid] + mred[4 + tid] + mred[8 + tid] + mred[12 + tid];
  }
  if (quad == 0)
#pragma unroll
    for (int t = 0; t < 2; ++t)
#pragma unroll
      for (int h = 0; h < 4; ++h)
        P[8 + h * 128 + (n0 + t * 16 + l16)] = pacc[t][h];
}

// ---------------- K_combine: merge partials, softmax, rho MLP, sigmoid ----------------
__global__ __launch_bounds__(256) void k_combine(
    const float* __restrict__ part,
    const float* __restrict__ rW0, const float* __restrict__ rb0,
    const float* __restrict__ rW1, const float* __restrict__ rb1,
    const float* __restrict__ rW2, const float* __restrict__ rb2,
    const float* __restrict__ rW3, const float* __restrict__ rb3,
    float* __restrict__ out) {
  __shared__ float mg[4], Ss[4], sc[36], agg[512], r1[128], r2[128], r3[128], p0[256];
  int tid = threadIdx.x;
  int b = blockIdx.x;
  const float* P = part + b * NPART * PART_STRIDE;
  if (tid < 4) {
    float m = -1e30f;
    for (int p = 0; p < NPART; ++p) m = fmaxf(m, P[p * PART_STRIDE + tid]);
    mg[tid] = m;
  }
  __syncthreads();
  if (tid < 36) {
    int p = tid >> 2, h = tid & 3;
    sc[tid] = expf(P[p * PART_STRIDE + h] - mg[h]);
  }
  __syncthreads();
  if (tid < 4) {
    float s = 0.f;
    for (int p = 0; p < NPART; ++p) s += P[p * PART_STRIDE + 4 + tid] * sc[p * 4 + tid];
    Ss[tid] = s;
  }
  __syncthreads();
  for (int idx = tid; idx < 512; idx += 256) {
    int h = idx >> 7;
    float a = 0.f;
    for (int p = 0; p < NPART; ++p) a = fmaf(P[p * PART_STRIDE + 8 + idx], sc[p * 4 + h], a);
    agg[idx] = a / Ss[h];
  }
  __syncthreads();
  const int col = tid & 127, half = tid >> 7;
  { // rho layer 0: K=512 split across 2 halves
    float a = 0.f;
    for (int k = half * 256; k < half * 256 + 256; ++k) a = fmaf(agg[k], rW0[k * 128 + col], a);
    p0[tid] = a;
  }
  __syncthreads();
  if (tid < 128) r1[tid] = fmaxf(rb0[tid] + p0[tid] + p0[128 + tid], 0.f);
  __syncthreads();
  {
    float a = 0.f;
    for (int k = half * 64; k < half * 64 + 64; ++k) a = fmaf(r1[k], rW1[k * 128 + col], a);
    p0[tid] = a;
  }
  __syncthreads();
  if (tid < 128) r2[tid] = fmaxf(rb1[tid] + p0[tid] + p0[128 + tid], 0.f);
  __syncthreads();
  {
    float a = 0.f;
    for (int k = half * 64; k < half * 64 + 64; ++k) a = fmaf(r2[k], rW2[k * 128 + col], a);
    p0[tid] = a;
  }
  __syncthreads();
  if (tid < 128) r3[tid] = fmaxf(rb2[tid] + p0[tid] + p0[128 + tid], 0.f);
  __syncthreads();
  if (tid < 128) p0[tid] = r3[tid] * rW3[tid];
  __syncthreads();
  if (tid == 0) {
    float a = rb3[0];
    for (int k = 0; k < 128; ++k) a += p0[k];
    out[b] = 1.f / (1.f + expf(-a));
  }
}

extern "C" void kernel_launch(void* const* d_in, const int* in_sizes, int n_in,
                              void* d_out, int out_size, void* d_ws, size_t ws_size,
                              hipStream_t stream) {
  const float* demo   = (const float*)d_in[0];
  const float* times  = (const float*)d_in[1];
  const float* values = (const float*)d_in[2];
  const int*   meas   = (const int*)d_in[3];
  // d_in[4] segment_ids: static layout repeat(arange(64), 4097) — unused
  const float* tsc = (const float*)d_in[5];
  const float* dW1 = (const float*)d_in[6];
  const float* db1 = (const float*)d_in[7];
  const float* dW2 = (const float*)d_in[8];
  const float* db2 = (const float*)d_in[9];
  const float* pW0 = (const float*)d_in[10];
  const float* pb0 = (const float*)d_in[11];
  const float* pW1 = (const float*)d_in[12];
  const float* pb1 = (const float*)d_in[13];
  const float* pW2 = (const float*)d_in[14];
  const float* pb2 = (const float*)d_in[15];
  const float* pW3 = (const float*)d_in[16];
  const float* pb3 = (const float*)d_in[17];
  // d_in[18..23] psi weights: provably dead — skipped
  const float* Wk  = (const float*)d_in[24];
  const float* Wq  = (const float*)d_in[25];
  const float* rW0 = (const float*)d_in[26];
  const float* rb0 = (const float*)d_in[27];
  const float* rW1 = (const float*)d_in[28];
  const float* rb1 = (const float*)d_in[29];
  const float* rW2 = (const float*)d_in[30];
  const float* rb2 = (const float*)d_in[31];
  const float* rW3 = (const float*)d_in[32];
  const float* rb3 = (const float*)d_in[33];
  float* ws = (float*)d_ws;
  float* partials = ws + OFF_PARTIALS;

  k_prep<<<226, 256, 0, stream>>>(demo, dW1, db1, dW2, db2, Wk, Wq,
                                  pW0, pW1, pW2, pW3, ws);
  k_main<<<513, 256, 0, stream>>>(times, values, meas, tsc, ws,
                                  pb0, pb1, pb2, pb3, partials);
  k_combine<<<64, 256, 0, stream>>>(partials, rW0, rb0, rW1, rb1, rW2, rb2, rW3, rb3,
                                    (float*)d_out);
}